// Round 1
// baseline (9556.680 us; speedup 1.0000x reference)
//
#include <hip/hip_runtime.h>
#include <math.h>

// Problem constants (B, T, D_IN, D_OUT) = (64, 1024, 512, 512)
#define BATCH   64
#define TSTEPS  1024
#define DIN     512
#define DH      512
#define MDIM    (BATCH * TSTEPS)   // 65536 rows of x viewed as [M, DIN]

// ---------------------------------------------------------------------------
// K1: XW[m][n] = sum_k X[m][k] * W[k][n] + bias[n]
// 64x64 tile per workgroup, 256 threads, 4x4 micro-tile per thread, BK=16.
// fp32 vector-ALU GEMM (no fp32 MFMA on CDNA4).
// ---------------------------------------------------------------------------
__global__ __launch_bounds__(256) void gemm_xw(const float* __restrict__ X,
                                               const float* __restrict__ W,
                                               const float* __restrict__ bias,
                                               float* __restrict__ XW) {
    __shared__ float As[16][68];   // [k][m], +4 pad keeps 16B alignment, breaks bank stride
    __shared__ float Bs[16][68];   // [k][n]

    const int tid = threadIdx.x;
    const int bx  = blockIdx.x & 7;    // n-tile index (512/64 = 8)
    const int by  = blockIdx.x >> 3;   // m-tile index (65536/64 = 1024)
    const int m0  = by * 64;
    const int n0  = bx * 64;

    const int ty = tid >> 4;           // 0..15 -> row group
    const int tx = tid & 15;           // 0..15 -> col group

    // staging index maps
    const int arow = tid >> 2;          // 0..63
    const int akq  = (tid & 3) * 4;     // 0,4,8,12
    const int brow = tid >> 4;          // 0..15
    const int bcq  = (tid & 15) * 4;    // 0..60

    float acc[4][4] = {{0.f}};

    for (int k0 = 0; k0 < DIN; k0 += 16) {
        // global loads issued before the barrier (latency overlap)
        float4 av = *(const float4*)&X[(size_t)(m0 + arow) * DIN + k0 + akq];
        float4 bv = *(const float4*)&W[(size_t)(k0 + brow) * DH + n0 + bcq];
        __syncthreads();   // previous tile's reads complete
        As[akq + 0][arow] = av.x;
        As[akq + 1][arow] = av.y;
        As[akq + 2][arow] = av.z;
        As[akq + 3][arow] = av.w;
        *(float4*)&Bs[brow][bcq] = bv;
        __syncthreads();

        #pragma unroll
        for (int k = 0; k < 16; ++k) {
            float4 a = *(const float4*)&As[k][ty * 4];
            float4 b = *(const float4*)&Bs[k][tx * 4];
            float ar[4] = {a.x, a.y, a.z, a.w};
            float br[4] = {b.x, b.y, b.z, b.w};
            #pragma unroll
            for (int i = 0; i < 4; ++i)
                #pragma unroll
                for (int j = 0; j < 4; ++j)
                    acc[i][j] = fmaf(ar[i], br[j], acc[i][j]);
        }
    }

    float4 bv = *(const float4*)&bias[n0 + tx * 4];
    const float br[4] = {bv.x, bv.y, bv.z, bv.w};
    #pragma unroll
    for (int i = 0; i < 4; ++i) {
        float4 o;
        o.x = acc[i][0] + br[0];
        o.y = acc[i][1] + br[1];
        o.z = acc[i][2] + br[2];
        o.w = acc[i][3] + br[3];
        *(float4*)&XW[(size_t)(m0 + ty * 4 + i) * DH + n0 + tx * 4] = o;
    }
}

// ---------------------------------------------------------------------------
// K2: sequential scan. One workgroup per batch element (batches independent,
// no inter-wg sync). 512 threads; thread t owns column t of h.
//   h_new[j] = tanh(xw[t][j] + sum_i h[i] * Wr[i][j])
// h lives in LDS (broadcast reads are free); Wr streams from per-XCD L2
// (1 MiB, fits; 8 wgs/XCD -> L2-BW-bound ~1.9 us/step by design for round 1).
// ---------------------------------------------------------------------------
__global__ __launch_bounds__(512) void rnn_scan(const float* __restrict__ XW,
                                                const float* __restrict__ Wr,
                                                float* __restrict__ Hout) {
    __shared__ float hs[DH];

    const int b   = blockIdx.x;
    const int tid = threadIdx.x;   // 0..511 == column j

    hs[tid] = 0.0f;                // h0 = 0
    __syncthreads();

    const float* xwb = XW + (size_t)b * TSTEPS * DH;

    float xwv  = xwb[tid];         // prefetched xw for t=0
    float hlast = 0.0f;

    for (int t = 0; t < TSTEPS; ++t) {
        float acc = 0.0f;
        // 512-long dot product: hs[i] is a wave-uniform LDS broadcast,
        // Wr[i*DH + tid] is a fully coalesced 256B/wave row read (L2 hit).
        #pragma unroll 32
        for (int i = 0; i < DH; ++i) {
            acc = fmaf(hs[i], Wr[(size_t)i * DH + tid], acc);
        }
        // prefetch next timestep's xw while the adds drain
        const int tn = (t + 1) & (TSTEPS - 1);
        float xwn = xwb[(size_t)tn * DH + tid];

        float h = tanhf(acc + xwv);
        hlast = h;
        __syncthreads();           // everyone done reading hs for step t
        hs[tid] = h;
        __syncthreads();           // h_new visible before step t+1 reads
        xwv = xwn;
    }

    Hout[(size_t)b * DH + tid] = hlast;
}

// ---------------------------------------------------------------------------
// launch
// ---------------------------------------------------------------------------
extern "C" void kernel_launch(void* const* d_in, const int* in_sizes, int n_in,
                              void* d_out, int out_size, void* d_ws, size_t ws_size,
                              hipStream_t stream) {
    const float* x  = (const float*)d_in[0];   // [64,1024,512]
    const float* W  = (const float*)d_in[1];   // [512,512]
    const float* Wr = (const float*)d_in[2];   // [512,512]
    const float* bv = (const float*)d_in[3];   // [512]
    float* out = (float*)d_out;                // [64,512]

    const size_t xw_bytes = (size_t)MDIM * DH * sizeof(float);  // 134 MB
    if (ws_size < xw_bytes) return;  // fail loudly (output untouched)
    float* xw = (float*)d_ws;

    // K1: xw = x @ W + b   (8192 tiles of 64x64)
    gemm_xw<<<dim3((MDIM / 64) * (DH / 64)), dim3(256), 0, stream>>>(x, W, bv, xw);

    // K2: sequential scan, one wg per batch
    rnn_scan<<<dim3(BATCH), dim3(512), 0, stream>>>(xw, Wr, out);
}

// Round 2
// 2280.034 us; speedup vs baseline: 4.1915x; 4.1915x over previous
//
#include <hip/hip_runtime.h>
#include <math.h>

// Problem constants (B, T, D_IN, D_OUT) = (64, 1024, 512, 512)
#define BATCH   64
#define TSTEPS  1024
#define DIN     512
#define DH      512
#define MDIM    (BATCH * TSTEPS)   // 65536 rows of x viewed as [M, DIN]

// K2 residency split: 256 row-pairs per column = VPAIRS in VGPRs + LPAIRS in LDS
#define VPAIRS  184                // row-pairs 0..183  (rows 0..367)  in registers
#define LPAIRS  72                 // row-pairs 184..255 (rows 368..511) in LDS
#define LSTRIDE 76                 // padded words/col: 76*4B=304 (16B aligned), gcd(76,32)=4
                                   // -> b128 reads spread 8 words/bank (same as baseline, no extra conflict)
// dynamic LDS: Wr slice [512][LSTRIDE] words + h double-buffer [2][256] words
#define LDS_WORDS (512 * LSTRIDE + 2 * 256)
#define LDS_BYTES (LDS_WORDS * 4)   // 157696 < 163840

typedef _Float16 h2_t __attribute__((ext_vector_type(2)));

__device__ inline unsigned short f2h_bits(float x) {
    _Float16 h = (_Float16)x;                       // v_cvt_f16_f32, RNE
    return __builtin_bit_cast(unsigned short, h);
}

__device__ inline unsigned int pack2h(float lo, float hi) {
    return (unsigned int)f2h_bits(lo) | ((unsigned int)f2h_bits(hi) << 16);
}

// packed-fp16 dot2 with fp32 accumulate: acc + a.x*b.x + a.y*b.y
__device__ inline float dot2h(unsigned int ha, unsigned int wb, float acc) {
#if __has_builtin(__builtin_amdgcn_fdot2)
    return __builtin_amdgcn_fdot2(__builtin_bit_cast(h2_t, ha),
                                  __builtin_bit_cast(h2_t, wb), acc, false);
#else
    float hl = (float)__builtin_bit_cast(h2_t, ha).x;
    float hh = (float)__builtin_bit_cast(h2_t, ha).y;
    float wl = (float)__builtin_bit_cast(h2_t, wb).x;
    float wh = (float)__builtin_bit_cast(h2_t, wb).y;
    return fmaf(hh, wh, fmaf(hl, wl, acc));
#endif
}

// ---------------------------------------------------------------------------
// K1: XW = X @ W + bias  (unchanged from round 1: ~420 us, not the bottleneck)
// ---------------------------------------------------------------------------
__global__ __launch_bounds__(256) void gemm_xw(const float* __restrict__ X,
                                               const float* __restrict__ W,
                                               const float* __restrict__ bias,
                                               float* __restrict__ XW) {
    __shared__ float As[16][68];
    __shared__ float Bs[16][68];

    const int tid = threadIdx.x;
    const int bx  = blockIdx.x & 7;
    const int by  = blockIdx.x >> 3;
    const int m0  = by * 64;
    const int n0  = bx * 64;

    const int ty = tid >> 4;
    const int tx = tid & 15;

    const int arow = tid >> 2;
    const int akq  = (tid & 3) * 4;
    const int brow = tid >> 4;
    const int bcq  = (tid & 15) * 4;

    float acc[4][4] = {{0.f}};

    for (int k0 = 0; k0 < DIN; k0 += 16) {
        float4 av = *(const float4*)&X[(size_t)(m0 + arow) * DIN + k0 + akq];
        float4 bv = *(const float4*)&W[(size_t)(k0 + brow) * DH + n0 + bcq];
        __syncthreads();
        As[akq + 0][arow] = av.x;
        As[akq + 1][arow] = av.y;
        As[akq + 2][arow] = av.z;
        As[akq + 3][arow] = av.w;
        *(float4*)&Bs[brow][bcq] = bv;
        __syncthreads();

        #pragma unroll
        for (int k = 0; k < 16; ++k) {
            float4 a = *(const float4*)&As[k][ty * 4];
            float4 b = *(const float4*)&Bs[k][tx * 4];
            float ar[4] = {a.x, a.y, a.z, a.w};
            float br[4] = {b.x, b.y, b.z, b.w};
            #pragma unroll
            for (int i = 0; i < 4; ++i)
                #pragma unroll
                for (int j = 0; j < 4; ++j)
                    acc[i][j] = fmaf(ar[i], br[j], acc[i][j]);
        }
    }

    float4 bv = *(const float4*)&bias[n0 + tx * 4];
    const float br[4] = {bv.x, bv.y, bv.z, bv.w};
    #pragma unroll
    for (int i = 0; i < 4; ++i) {
        float4 o;
        o.x = acc[i][0] + br[0];
        o.y = acc[i][1] + br[1];
        o.z = acc[i][2] + br[2];
        o.w = acc[i][3] + br[3];
        *(float4*)&XW[(size_t)(m0 + ty * 4 + i) * DH + n0 + tx * 4] = o;
    }
}

// ---------------------------------------------------------------------------
// K2: sequential scan with ON-CU-RESIDENT Wr (fp16 packed pairs).
// One wg per batch (64 wgs, no cross-wg sync). Thread j owns output column j.
//   - Wr column j, rows 0..367: 184 packed words held in VGPRs for the whole kernel
//   - Wr rows 368..511 (all cols): 72 packed words/col in LDS ([col][pair], stride 76)
//   - h: packed fp16 pairs in LDS, double-buffered -> 1 barrier/step
// Per-step VMEM: one xw float per thread (2 KB/CU). Per-step work: 256 dot2 +
// 82 ds_read_b128 per thread. No streaming of Wr => the round-1 per-CU VMEM
// wall (1 MB/step @ ~64 B/cyc = 6.8 us) is gone.
// ---------------------------------------------------------------------------
__global__ __launch_bounds__(512, 2) void rnn_scan2(const float* __restrict__ XW,
                                                    const float* __restrict__ Wr,
                                                    float* __restrict__ Hout) {
    extern __shared__ unsigned int lds[];
    unsigned int* wrl  = lds;                       // [512][LSTRIDE]
    unsigned int* hbuf = lds + 512 * LSTRIDE;       // [2][256]

    const int b = blockIdx.x;
    const int j = threadIdx.x;                      // column 0..511

    // ---- one-time: load + convert Wr column j into registers (coalesced per row)
    unsigned int wreg[VPAIRS];
    #pragma unroll
    for (int p = 0; p < VPAIRS; ++p) {
        float lo = Wr[(size_t)(2 * p)     * DH + j];
        float hi = Wr[(size_t)(2 * p + 1) * DH + j];
        wreg[p] = pack2h(lo, hi);
    }
    // ---- one-time: rows 368..511 for column j into LDS (transposed layout)
    unsigned int* wl_my = wrl + (size_t)j * LSTRIDE;
    #pragma unroll
    for (int p = 0; p < LPAIRS; ++p) {
        int r0 = 2 * (VPAIRS + p);
        float lo = Wr[(size_t)r0       * DH + j];
        float hi = Wr[(size_t)(r0 + 1) * DH + j];
        wl_my[p] = pack2h(lo, hi);
    }
    // h0 = 0 in both buffers (512 words total)
    hbuf[j] = 0u;
    __syncthreads();

    const float* xwb = XW + (size_t)b * TSTEPS * DH + j;
    float xwv  = xwb[0];
    float h_f  = 0.0f;
    int   cur  = 0;

    const unsigned int* wl = wrl + (size_t)j * LSTRIDE;

    for (int t = 0; t < TSTEPS; ++t) {
        const unsigned int* hp = hbuf + cur * 256;

        // prefetch next xw early (clamped; uniform index)
        const int tn = (t + 1 < TSTEPS) ? (t + 1) : (TSTEPS - 1);
        float xwn = xwb[(size_t)tn * DH];

        float a0 = 0.f, a1 = 0.f, a2 = 0.f, a3 = 0.f;

        // register-resident part: pairs 0..183 (h broadcast reads, b128)
        #pragma unroll
        for (int p = 0; p < VPAIRS; p += 4) {
            uint4 hv = *(const uint4*)(hp + p);
            a0 = dot2h(hv.x, wreg[p + 0], a0);
            a1 = dot2h(hv.y, wreg[p + 1], a1);
            a2 = dot2h(hv.z, wreg[p + 2], a2);
            a3 = dot2h(hv.w, wreg[p + 3], a3);
        }
        // LDS-resident part: pairs 184..255
        #pragma unroll
        for (int p = 0; p < LPAIRS; p += 4) {
            uint4 hv = *(const uint4*)(hp + VPAIRS + p);
            uint4 wv = *(const uint4*)(wl + p);
            a0 = dot2h(hv.x, wv.x, a0);
            a1 = dot2h(hv.y, wv.y, a1);
            a2 = dot2h(hv.z, wv.z, a2);
            a3 = dot2h(hv.w, wv.w, a3);
        }

        float z = ((a0 + a1) + (a2 + a3)) + xwv;
        h_f = tanhf(z);

        // publish h as fp16 into the other buffer (2 lanes/word halves: conflict-free)
        unsigned short* hbn = (unsigned short*)(hbuf + ((cur ^ 1) * 256));
        hbn[j] = f2h_bits(h_f);

        __syncthreads();
        cur ^= 1;
        xwv = xwn;
    }

    Hout[(size_t)b * DH + j] = h_f;
}

// ---------------------------------------------------------------------------
// launch
// ---------------------------------------------------------------------------
extern "C" void kernel_launch(void* const* d_in, const int* in_sizes, int n_in,
                              void* d_out, int out_size, void* d_ws, size_t ws_size,
                              hipStream_t stream) {
    const float* x  = (const float*)d_in[0];   // [64,1024,512]
    const float* W  = (const float*)d_in[1];   // [512,512]
    const float* Wr = (const float*)d_in[2];   // [512,512]
    const float* bv = (const float*)d_in[3];   // [512]
    float* out = (float*)d_out;                // [64,512]

    const size_t xw_bytes = (size_t)MDIM * DH * sizeof(float);  // 134.2 MB
    if (ws_size < xw_bytes) return;
    float* xw = (float*)d_ws;

    // opt-in to >64KB dynamic LDS (module-level setting; capture-safe)
    static int lds_attr_done = 0;  // idempotent attribute, safe to set every call
    (void)lds_attr_done;
    hipFuncSetAttribute((const void*)rnn_scan2,
                        hipFuncAttributeMaxDynamicSharedMemorySize, LDS_BYTES);

    // K1: xw = x @ W + b
    gemm_xw<<<dim3((MDIM / 64) * (DH / 64)), dim3(256), 0, stream>>>(x, W, bv, xw);

    // K2: resident-Wr sequential scan, one wg per batch
    rnn_scan2<<<dim3(BATCH), dim3(512), LDS_BYTES, stream>>>(xw, Wr, out);
}